// Round 1
// baseline (566.648 us; speedup 1.0000x reference)
//
#include <hip/hip_runtime.h>

// Correlation cost volume: B=4, C=256, H=W=192, MAX_DISP=4 -> 81 displacements.
// out[b, dy*9+dx, y, x] = (1/C) * sum_c F[b,c,y,x] * Spad[b,c,y+dy-4,x+dx-4]

#define MAXD 4
#define WINW 9
#define NDISP 81

constexpr int B_ = 4, C_ = 256, H_ = 192, W_ = 192;
constexpr int TH = 4;                    // output rows per block
constexpr int TW = 64;                   // output cols per block
constexpr int CC = 8;                    // channels staged per chunk
constexpr int SROWS = TH + 2 * MAXD;     // 12
constexpr int SCOLS = TW + 2 * MAXD;     // 72
constexpr int F_STRIDE = 68;             // padded from 64 (bank spread)
constexpr int S_STRIDE = 72;
constexpr int F_CH = TH * F_STRIDE;      // 272 floats per staged channel
constexpr int S_CH = SROWS * S_STRIDE;   // 864 floats per staged channel
constexpr int NTHREADS = 576;            // 9 waves: wave id == dy

__global__ __launch_bounds__(NTHREADS)
void corr_kernel(const float* __restrict__ F, const float* __restrict__ S,
                 float* __restrict__ O) {
    __shared__ float ldsF[CC * F_CH];    // 8.5 KB
    __shared__ float ldsS[CC * S_CH];    // 27 KB

    const int tid  = threadIdx.x;
    const int y0   = blockIdx.x * TH;
    const int x0   = blockIdx.y * TW;
    const int b    = blockIdx.z;
    const int dy   = tid >> 6;           // wave index = dy in [0,9)
    const int lane = tid & 63;
    const int xg   = lane & 15;          // x-group of 4 pixels
    const int yth  = lane >> 4;          // row within tile, [0,4)

    float acc[WINW][4];
    #pragma unroll
    for (int dx = 0; dx < WINW; ++dx)
        #pragma unroll
        for (int j = 0; j < 4; ++j) acc[dx][j] = 0.f;

    const long planeHW = (long)H_ * W_;  // 36864
    const float* Fb = F + (long)b * C_ * planeHW;
    const float* Sb = S + (long)b * C_ * planeHW;

    for (int c0 = 0; c0 < C_; c0 += CC) {
        __syncthreads();   // previous chunk's compute done before overwrite

        // ---- stage F tile: CC*TH*(TW/4) = 512 float4, fully in-bounds ----
        {
            int i = tid;
            if (i < CC * TH * (TW / 4)) {
                int cc  = i >> 6;        // /64
                int rem = i & 63;
                int yr  = rem >> 4;
                int cg  = rem & 15;
                const float4 v = *(const float4*)(Fb + (long)(c0 + cc) * planeHW
                                                  + (long)(y0 + yr) * W_ + x0 + 4 * cg);
                *(float4*)(&ldsF[cc * F_CH + yr * F_STRIDE + 4 * cg]) = v;
            }
        }
        // ---- stage S tile: CC*SROWS*(SCOLS/4) = 1728 float4 = 3 per thread ----
        #pragma unroll
        for (int k = 0; k < 3; ++k) {
            int i   = tid + k * NTHREADS;
            int cc  = i / (SROWS * (SCOLS / 4));          // /216
            int rem = i - cc * (SROWS * (SCOLS / 4));
            int r   = rem / (SCOLS / 4);                  // /18
            int cg  = rem - r * (SCOLS / 4);
            int ys  = y0 - MAXD + r;
            int xs  = x0 - MAXD + 4 * cg;
            float4 v = make_float4(0.f, 0.f, 0.f, 0.f);
            // x-groups are 4-aligned: each float4 is fully in- or out-of-bounds
            if ((unsigned)ys < (unsigned)H_ && (unsigned)xs <= (unsigned)(W_ - 4)) {
                v = *(const float4*)(Sb + (long)(c0 + cc) * planeHW + (long)ys * W_ + xs);
            }
            *(float4*)(&ldsS[cc * S_CH + r * S_STRIDE + 4 * cg]) = v;
        }
        __syncthreads();

        // ---- compute: per channel, 4x ds_read_b128 -> 36 FMAs ----
        #pragma unroll
        for (int cc = 0; cc < CC; ++cc) {
            const float4 f = *(const float4*)(&ldsF[cc * F_CH + yth * F_STRIDE + 4 * xg]);
            const int sb = cc * S_CH + (yth + dy) * S_STRIDE + 4 * xg;
            const float4 w0 = *(const float4*)(&ldsS[sb]);
            const float4 w1 = *(const float4*)(&ldsS[sb + 4]);
            const float4 w2 = *(const float4*)(&ldsS[sb + 8]);
            const float w[12] = {w0.x, w0.y, w0.z, w0.w,
                                 w1.x, w1.y, w1.z, w1.w,
                                 w2.x, w2.y, w2.z, w2.w};
            #pragma unroll
            for (int dx = 0; dx < WINW; ++dx) {
                acc[dx][0] += f.x * w[dx];
                acc[dx][1] += f.y * w[dx + 1];
                acc[dx][2] += f.z * w[dx + 2];
                acc[dx][3] += f.w * w[dx + 3];
            }
        }
    }

    // ---- epilogue: 9 coalesced float4 stores per thread ----
    const float scale = 1.0f / (float)C_;
    #pragma unroll
    for (int dx = 0; dx < WINW; ++dx) {
        float4 o;
        o.x = acc[dx][0] * scale;
        o.y = acc[dx][1] * scale;
        o.z = acc[dx][2] * scale;
        o.w = acc[dx][3] * scale;
        const int d = dy * WINW + dx;
        float* dst = O + ((long)(b * NDISP + d) * H_ + (y0 + yth)) * W_ + x0 + 4 * xg;
        *(float4*)dst = o;
    }
}

extern "C" void kernel_launch(void* const* d_in, const int* in_sizes, int n_in,
                              void* d_out, int out_size, void* d_ws, size_t ws_size,
                              hipStream_t stream) {
    const float* F = (const float*)d_in[0];
    const float* S = (const float*)d_in[1];
    float* O = (float*)d_out;
    dim3 grid(H_ / TH, W_ / TW, B_);   // 48 x 3 x 4 = 576 blocks
    dim3 block(NTHREADS);
    corr_kernel<<<grid, block, 0, stream>>>(F, S, O);
}